// Round 1
// baseline (674.759 us; speedup 1.0000x reference)
//
#include <hip/hip_runtime.h>
#include <hip/hip_bf16.h>

#define TOKENS 8192
#define NOUT   4096
#define KIN    4096

typedef __attribute__((ext_vector_type(8))) short short8;   // 8 bf16 (4 VGPRs)
typedef __attribute__((ext_vector_type(4))) float f32x4;    // MFMA accumulator

// RNE float -> bf16 bits
__device__ __forceinline__ short f2bf(float f) {
  union { float f; unsigned u; } v; v.f = f;
  unsigned r = v.u + 0x7fffu + ((v.u >> 16) & 1u);
  return (short)(r >> 16);
}

// async global -> LDS, 16B per lane (global_load_lds_dwordx4)
__device__ __forceinline__ void async_copy16(const void* g, void* l) {
  __builtin_amdgcn_global_load_lds(
      (const __attribute__((address_space(1))) void*)g,
      (__attribute__((address_space(3))) void*)l, 16, 0, 0);
}

// Gather-pack: wb[i] = bf16(weight[idx[i]]), 8 elems/thread
__global__ void pack_w_kernel(const int4* __restrict__ idx,
                              const float* __restrict__ w,
                              short8* __restrict__ wb) {
  size_t t = (size_t)blockIdx.x * blockDim.x + threadIdx.x;
  int4 a = idx[2 * t];
  int4 b = idx[2 * t + 1];
  short8 o;
  o[0] = f2bf(w[a.x]); o[1] = f2bf(w[a.y]);
  o[2] = f2bf(w[a.z]); o[3] = f2bf(w[a.w]);
  o[4] = f2bf(w[b.x]); o[5] = f2bf(w[b.y]);
  o[6] = f2bf(w[b.z]); o[7] = f2bf(w[b.w]);
  wb[t] = o;
}

// Cast-pack: xb[i] = bf16(x[i]), 8 elems/thread
__global__ void pack_x_kernel(const float4* __restrict__ x,
                              short8* __restrict__ xb) {
  size_t t = (size_t)blockIdx.x * blockDim.x + threadIdx.x;
  float4 a = x[2 * t];
  float4 b = x[2 * t + 1];
  short8 o;
  o[0] = f2bf(a.x); o[1] = f2bf(a.y); o[2] = f2bf(a.z); o[3] = f2bf(a.w);
  o[4] = f2bf(b.x); o[5] = f2bf(b.y); o[6] = f2bf(b.z); o[7] = f2bf(b.w);
  xb[t] = o;
}

#define BM 128
#define BN 128
#define BK 32

// NT bf16 GEMM (m97 structure): A [M][K], B [N][K] (both K-major bf16),
// C[m][n] = sum_k A[m][k]*B[n][k] + bias[n], fp32 out.
__global__ void gemm_kernel(const short* __restrict__ A,
                            const short* __restrict__ B,
                            const float* __restrict__ bias,
                            float* __restrict__ C) {
  __shared__ __align__(128) short As[BM * BK];  // 8 KiB
  __shared__ __align__(128) short Bs[BN * BK];  // 8 KiB

  const int tid  = threadIdx.x;
  const int lane = tid & 63;
  const int wave = tid >> 6;          // 4 waves, 2x2
  const int wr = wave >> 1;
  const int wc = wave & 1;

  // XCD-aware bijective swizzle (nwg = 2048, divisible by 8)
  const int nwg = gridDim.x;
  const int cpx = nwg >> 3;
  const int b   = blockIdx.x;
  const int swz = (b & 7) * cpx + (b >> 3);
  const int bm  = swz & 63;   // 64 row-blocks (fastest -> B panel reused in L2)
  const int bn  = swz >> 6;   // 32 col-blocks

  const short* a_base = A + (size_t)(bm * BM) * KIN;
  const short* b_base = B + (size_t)(bn * BN) * KIN;

  f32x4 acc[4][4] = {};

  // staging decomposition: 256 thr x 16B = 4KB per instr; tile 8KB = 2 instrs
  const int sr = tid >> 2;            // row 0..63 within half-tile
  const int sc = (tid & 3) * 8;       // k-offset (elements) of 16B chunk

  for (int k0 = 0; k0 < KIN; k0 += BK) {
    __syncthreads();  // previous iteration's LDS reads done before overwrite
    async_copy16(a_base + (size_t)sr * KIN + k0 + sc,        &As[sr * BK + sc]);
    async_copy16(a_base + (size_t)(sr + 64) * KIN + k0 + sc, &As[(sr + 64) * BK + sc]);
    async_copy16(b_base + (size_t)sr * KIN + k0 + sc,        &Bs[sr * BK + sc]);
    async_copy16(b_base + (size_t)(sr + 64) * KIN + k0 + sc, &Bs[(sr + 64) * BK + sc]);
    __syncthreads();  // drains vmcnt -> tiles ready

    const int kg   = (lane >> 4) * 8;      // k-group of this lane
    const int arow = wr * 64 + (lane & 15);
    const int bcol = wc * 64 + (lane & 15);
    short8 af[4], bfr[4];
#pragma unroll
    for (int m = 0; m < 4; ++m)
      af[m] = *(const short8*)&As[(arow + m * 16) * BK + kg];
#pragma unroll
    for (int n = 0; n < 4; ++n)
      bfr[n] = *(const short8*)&Bs[(bcol + n * 16) * BK + kg];
#pragma unroll
    for (int m = 0; m < 4; ++m)
#pragma unroll
      for (int n = 0; n < 4; ++n)
        acc[m][n] = __builtin_amdgcn_mfma_f32_16x16x32_bf16(af[m], bfr[n], acc[m][n], 0, 0, 0);
  }

  // epilogue: C/D map col = lane&15, row = (lane>>4)*4 + reg (m89/m91 verified)
  const int crow0 = bm * BM + wr * 64 + (lane >> 4) * 4;
  const int ccol0 = bn * BN + wc * 64 + (lane & 15);
  float bs[4];
#pragma unroll
  for (int n = 0; n < 4; ++n) bs[n] = bias[ccol0 + n * 16];
#pragma unroll
  for (int m = 0; m < 4; ++m) {
#pragma unroll
    for (int j = 0; j < 4; ++j) {
      float* crow = C + (size_t)(crow0 + m * 16 + j) * NOUT;
#pragma unroll
      for (int n = 0; n < 4; ++n)
        crow[ccol0 + n * 16] = acc[m][n][j] + bs[n];
    }
  }
}

extern "C" void kernel_launch(void* const* d_in, const int* in_sizes, int n_in,
                              void* d_out, int out_size, void* d_ws, size_t ws_size,
                              hipStream_t stream) {
  const float* x      = (const float*)d_in[0];
  const float* weight = (const float*)d_in[1];
  const float* bias   = (const float*)d_in[2];
  const int*   idx    = (const int*)d_in[3];
  float* out = (float*)d_out;

  // workspace layout: [0, 32MiB) W bf16 [NOUT][KIN]; [32MiB, 96MiB) x bf16 [TOKENS][KIN]
  short* wb = (short*)d_ws;
  short* xb = (short*)((char*)d_ws + (size_t)NOUT * KIN * sizeof(short));

  pack_w_kernel<<<((size_t)NOUT * KIN) / (8 * 256), 256, 0, stream>>>(
      (const int4*)idx, weight, (short8*)wb);
  pack_x_kernel<<<((size_t)TOKENS * KIN) / (8 * 256), 256, 0, stream>>>(
      (const float4*)x, (short8*)xb);
  gemm_kernel<<<(TOKENS / BM) * (NOUT / BN), 256, 0, stream>>>(xb, wb, bias, out);
}

// Round 2
// 590.949 us; speedup vs baseline: 1.1418x; 1.1418x over previous
//
#include <hip/hip_runtime.h>
#include <hip/hip_bf16.h>

#define TOKENS 8192
#define NOUT   4096
#define KIN    4096

typedef __attribute__((ext_vector_type(8))) short short8;   // 8 bf16
typedef __attribute__((ext_vector_type(4))) float f32x4;    // MFMA accumulator

// RNE float -> bf16 bits
__device__ __forceinline__ short f2bf(float f) {
  union { float f; unsigned u; } v; v.f = f;
  unsigned r = v.u + 0x7fffu + ((v.u >> 16) & 1u);
  return (short)(r >> 16);
}

// async global -> LDS, 16B per lane (global_load_lds_dwordx4)
__device__ __forceinline__ void async_copy16(const void* g, void* l) {
  __builtin_amdgcn_global_load_lds(
      (const __attribute__((address_space(1))) void*)g,
      (__attribute__((address_space(3))) void*)l, 16, 0, 0);
}

// Gather-pack: wb[i] = bf16(weight[idx[i]]), 8 elems/thread
__global__ void pack_w_kernel(const int4* __restrict__ idx,
                              const float* __restrict__ w,
                              short8* __restrict__ wb) {
  size_t t = (size_t)blockIdx.x * blockDim.x + threadIdx.x;
  int4 a = idx[2 * t];
  int4 b = idx[2 * t + 1];
  short8 o;
  o[0] = f2bf(w[a.x]); o[1] = f2bf(w[a.y]);
  o[2] = f2bf(w[a.z]); o[3] = f2bf(w[a.w]);
  o[4] = f2bf(w[b.x]); o[5] = f2bf(w[b.y]);
  o[6] = f2bf(w[b.z]); o[7] = f2bf(w[b.w]);
  wb[t] = o;
}

// Cast-pack: xb[i] = bf16(x[i]), 8 elems/thread
__global__ void pack_x_kernel(const float4* __restrict__ x,
                              short8* __restrict__ xb) {
  size_t t = (size_t)blockIdx.x * blockDim.x + threadIdx.x;
  float4 a = x[2 * t];
  float4 b = x[2 * t + 1];
  short8 o;
  o[0] = f2bf(a.x); o[1] = f2bf(a.y); o[2] = f2bf(a.z); o[3] = f2bf(a.w);
  o[4] = f2bf(b.x); o[5] = f2bf(b.y); o[6] = f2bf(b.z); o[7] = f2bf(b.w);
  xb[t] = o;
}

// ---------------- 256x256 8-phase bf16 GEMM (T2+T3+T4+T5) ----------------
// A [M][K], B [N][K] bf16 K-major; C = A*B^T + bias, fp32.
#define BM 256
#define BN 256
#define BK 64
#define NT    (KIN / BK)   // 64 K-tiles
#define NITER (NT / 2)     // 32 iterations, 2 tiles each

#define BARX()  __builtin_amdgcn_s_barrier()
#define FENCE() __builtin_amdgcn_sched_barrier(0)
#define WAITVM(N) asm volatile("s_waitcnt vmcnt(" #N ")" ::: "memory")

__global__ __launch_bounds__(512, 2) void gemm_kernel(const short* __restrict__ A,
                                                      const short* __restrict__ B,
                                                      const float* __restrict__ bias,
                                                      float* __restrict__ C) {
  __shared__ short As[2][BM * BK];  // 2 x 32 KiB
  __shared__ short Bs[2][BN * BK];  // 2 x 32 KiB  (total 128 KiB)

  const int tid  = threadIdx.x;
  const int lane = tid & 63;
  const int wave = tid >> 6;   // 8 waves: 2 (M) x 4 (N)
  const int wr = wave >> 2;    // 0..1 -> 128 rows each
  const int wc = wave & 3;     // 0..3 -> 64 cols each

  // XCD-bijective swizzle: 512 wgs, 64 consecutive per XCD; bm fastest
  const int b   = blockIdx.x;
  const int swz = (b & 7) * 64 + (b >> 3);
  const int bm  = swz & 31;    // 32 row-blocks
  const int bn  = swz >> 5;    // 16 col-blocks

  // ---- staging (linear LDS dest; inverse-swizzled global source) ----
  // one issue = 64 rows x 64 cols bf16 = 8KB; row = tid>>3, chunk = tid&7
  const int srow = tid >> 3;                        // 0..63
  const int sch  = ((tid & 7) ^ (srow & 7)) * 8;    // XOR-permuted 16B chunk
  const short* aS = A + (size_t)(bm * 256 + srow) * KIN + sch;
  const short* bS = B + (size_t)(bn * 256 + srow) * KIN + sch;
  short* aD0 = &As[0][tid * 8];
  short* aD1 = &As[1][tid * 8];
  short* bD0 = &Bs[0][tid * 8];
  short* bD1 = &Bs[1][tid * 8];

#define STG_A(BUF, BLK, T) async_copy16(aS + (size_t)(BLK) * 64 * KIN + (size_t)(T) * 64, \
                                        ((BUF) ? aD1 : aD0) + (BLK) * 4096)
#define STG_B(BUF, BLK, T) async_copy16(bS + (size_t)(BLK) * 64 * KIN + (size_t)(T) * 64, \
                                        ((BUF) ? bD1 : bD0) + (BLK) * 4096)

  // ---- fragment LDS byte offsets (swizzled read) ----
  const int l15   = lane & 15;
  const int sw    = (l15 & 7) << 4;                 // row&7 -> 16B slot XOR
  const int lanek = (lane >> 4) * 16;               // k-group byte offset
  int csw[2];
  csw[0] = (0  + lanek) ^ sw;
  csw[1] = (64 + lanek) ^ sw;
  const int aBase = (wr * 128 + l15) * 128;         // bytes
  const int bBase = (wc * 64  + l15) * 128;

  short8 af[4][2];        // A frags: 4 m-frags x 2 k-subs (current m-half)
  short8 bfr[2][2][2];    // B frags: both n-halves x 2 n-frags x 2 k-subs
  f32x4 acc[8][4] = {};   // 8 m-frags x 4 n-frags

#define RD_A(BUF, MH) { const char* _p = (const char*)((BUF) ? As[1] : As[0]) + aBase + (MH) * 8192; \
  _Pragma("unroll") for (int mf = 0; mf < 4; ++mf) \
  _Pragma("unroll") for (int ks = 0; ks < 2; ++ks) \
    af[mf][ks] = *(const short8*)(_p + mf * 2048 + csw[ks]); }

#define RD_B(BUF, NH) { const char* _p = (const char*)((BUF) ? Bs[1] : Bs[0]) + bBase + (NH) * 4096; \
  _Pragma("unroll") for (int nf = 0; nf < 2; ++nf) \
  _Pragma("unroll") for (int ks = 0; ks < 2; ++ks) \
    bfr[NH][nf][ks] = *(const short8*)(_p + nf * 2048 + csw[ks]); }

#define MM(MH, NH) { __builtin_amdgcn_s_setprio(1); \
  _Pragma("unroll") for (int mf = 0; mf < 4; ++mf) \
  _Pragma("unroll") for (int nf = 0; nf < 2; ++nf) \
  _Pragma("unroll") for (int ks = 0; ks < 2; ++ks) \
    acc[(MH) * 4 + mf][(NH) * 2 + nf] = __builtin_amdgcn_mfma_f32_16x16x32_bf16( \
        af[mf][ks], bfr[NH][nf][ks], acc[(MH) * 4 + mf][(NH) * 2 + nf], 0, 0, 0); \
  __builtin_amdgcn_s_setprio(0); }

  // ---- prologue: tile0 -> buf0 (8 issues), tile1 A-blocks 0,2 -> buf1 ----
  STG_A(0, 0, 0); STG_A(0, 1, 0); STG_A(0, 2, 0); STG_A(0, 3, 0);
  STG_B(0, 0, 0); STG_B(0, 1, 0); STG_B(0, 2, 0); STG_B(0, 3, 0);
  STG_A(1, 0, 1); STG_A(1, 2, 1);
  WAITVM(2); FENCE(); BARX();   // buf0 landed (buf1.A0/A2 still in flight)

  for (int it = 0; it < NITER; ++it) {
    const int t1  = 2 * it + 1;
    const int tn0 = 2 * it + 2;
    const int tn1 = 2 * it + 3;
    const bool pf = (it < NITER - 1);

    // ph1: buf0 (mh0,nh0); stage buf1 A-blocks 1,3 (tile t1; regions last read prev ph7)
    RD_A(0, 0); RD_B(0, 0);
    STG_A(1, 1, t1); STG_A(1, 3, t1);
    BARX(); MM(0, 0); BARX();
    // ph2: buf0 (mh0,nh1); stage buf1 B-blocks 0,1 (last read prev ph6)
    RD_B(0, 1);
    STG_B(1, 0, t1); STG_B(1, 1, t1);
    BARX(); MM(0, 1); BARX();
    // ph3: buf0 (mh1,nh0); stage buf1 B-blocks 2,3
    RD_A(0, 1);
    STG_B(1, 2, t1); STG_B(1, 3, t1);
    BARX(); MM(1, 0); BARX();
    // ph4: buf0 (mh1,nh1); stage buf0 A-blocks 0,2 for next tile (last read ph1)
    if (pf) { STG_A(0, 0, tn0); STG_A(0, 2, tn0); }
    BARX(); MM(1, 1);
    // counted drain: everything except ph4's own 2 issues has landed -> buf1 ready
    if (pf) { WAITVM(2); } else { WAITVM(0); }
    FENCE(); BARX();

    // ph5: buf1 (mh0,nh0); stage buf0 A-blocks 1,3 (last read ph3)
    RD_A(1, 0); RD_B(1, 0);
    if (pf) { STG_A(0, 1, tn0); STG_A(0, 3, tn0); }
    BARX(); MM(0, 0); BARX();
    // ph6: buf1 (mh0,nh1); stage buf0 B-blocks 0,1 (last read ph1/ph2)
    RD_B(1, 1);
    if (pf) { STG_B(0, 0, tn0); STG_B(0, 1, tn0); }
    BARX(); MM(0, 1); BARX();
    // ph7: buf1 (mh1,nh0); stage buf0 B-blocks 2,3
    RD_A(1, 1);
    if (pf) { STG_B(0, 2, tn0); STG_B(0, 3, tn0); }
    BARX(); MM(1, 0); BARX();
    // ph8: buf1 (mh1,nh1); stage buf1 A-blocks 0,2 for tile t1+2 (last read ph5)
    if (pf) { STG_A(1, 0, tn1); STG_A(1, 2, tn1); }
    BARX(); MM(1, 1);
    WAITVM(2); FENCE(); BARX();  // buf0 (ph4-7 stages) landed before next ph1 reads
  }

  // ---- epilogue: C/D layout col=lane&15, row=(lane>>4)*4+reg ----
  const int crow0 = bm * 256 + wr * 128 + (lane >> 4) * 4;
  const int ccol0 = bn * 256 + wc * 64 + l15;
  float bsv[4];
#pragma unroll
  for (int nf = 0; nf < 4; ++nf) bsv[nf] = bias[ccol0 + nf * 16];
#pragma unroll
  for (int mf = 0; mf < 8; ++mf) {
#pragma unroll
    for (int j = 0; j < 4; ++j) {
      float* cr = C + (size_t)(crow0 + mf * 16 + j) * NOUT;
#pragma unroll
      for (int nf = 0; nf < 4; ++nf)
        cr[ccol0 + nf * 16] = acc[mf][nf][j] + bsv[nf];
    }
  }
}

extern "C" void kernel_launch(void* const* d_in, const int* in_sizes, int n_in,
                              void* d_out, int out_size, void* d_ws, size_t ws_size,
                              hipStream_t stream) {
  const float* x      = (const float*)d_in[0];
  const float* weight = (const float*)d_in[1];
  const float* bias   = (const float*)d_in[2];
  const int*   idx    = (const int*)d_in[3];
  float* out = (float*)d_out;

  // ws: [0,32MiB) W bf16 [NOUT][KIN]; [32,96MiB) x bf16 [TOKENS][KIN]
  short* wb = (short*)d_ws;
  short* xb = (short*)((char*)d_ws + (size_t)NOUT * KIN * sizeof(short));

  pack_w_kernel<<<((size_t)NOUT * KIN) / (8 * 256), 256, 0, stream>>>(
      (const int4*)idx, weight, (short8*)wb);
  pack_x_kernel<<<((size_t)TOKENS * KIN) / (8 * 256), 256, 0, stream>>>(
      (const float4*)x, (short8*)xb);
  gemm_kernel<<<(TOKENS / BM) * (NOUT / BN), 512, 0, stream>>>(xb, wb, bias, out);
}